// Round 10
// baseline (397.862 us; speedup 1.0000x reference)
//
#include <hip/hip_runtime.h>
#include <hip/hip_bf16.h>
#include <math.h>

#define E_ 32
#define K_ 4
#define H_ 1024
#define I_ 1024
#define T_ 1024
#define TWO_I 2048

typedef __attribute__((ext_vector_type(4))) float float4v;
typedef __attribute__((ext_vector_type(8))) short short8v;
typedef __attribute__((ext_vector_type(4))) short short4v;

__device__ __forceinline__ unsigned short f2bf(float f) {
    unsigned u = __float_as_uint(f);
    u = (u + 0x7FFFu + ((u >> 16) & 1u)) >> 16;   // RNE (epilogue scalar use only)
    return (unsigned short)u;
}
// packed RNE f32->bf16 via HW instruction: 2 els / instr
__device__ __forceinline__ short4v cvt4(float4v v) {
    union { unsigned u[2]; short4v s; } r;
    asm("v_cvt_pk_bf16_f32 %0, %1, %2" : "=v"(r.u[0]) : "v"(v[0]), "v"(v[1]));
    asm("v_cvt_pk_bf16_f32 %0, %1, %2" : "=v"(r.u[1]) : "v"(v[2]), "v"(v[3]));
    return r.s;
}

// ---------------- prep: zero out+counts AND hs f32->bf16 (fused)
__global__ __launch_bounds__(256) void prep_kernel(
    const float* __restrict__ hs, unsigned short* __restrict__ hsb,
    float* __restrict__ out, int* __restrict__ counts) {
    int i = blockIdx.x * 256 + threadIdx.x;
    float4v v = *(const float4v*)(hs + (size_t)i * 4);
    *(short4v*)(hsb + (size_t)i * 4) = cvt4(v);
    *(float4v*)(out + (size_t)i * 4) = (float4v){0.f, 0.f, 0.f, 0.f};
    if (blockIdx.x == 0 && threadIdx.x < E_) counts[threadIdx.x] = 0;
}

// ---------------- router: 4 tokens/block, one wave/token, wave-parallel top-4
__global__ __launch_bounds__(256) void router_kernel(
    const float* __restrict__ hs, const float* __restrict__ gw,
    const float* __restrict__ gb, int* __restrict__ counts,
    int* __restrict__ token_list, float* __restrict__ weight_list) {
    int wv = threadIdx.x >> 6, lane = threadIdx.x & 63;
    int t = blockIdx.x * 4 + wv;
    int e = lane & 31;
    int half = lane >> 5;
    const float* hrow = hs + (size_t)t * H_;
    const float* gcol = gw + e;
    float a0 = 0.f, a1 = 0.f;
    int hb = half * 512;
#pragma unroll 4
    for (int h = 0; h < 512; h += 2) {
        a0 = fmaf(hrow[hb + h],     gcol[(size_t)(hb + h) * E_], a0);
        a1 = fmaf(hrow[hb + h + 1], gcol[(size_t)(hb + h + 1) * E_], a1);
    }
    float part = a0 + a1;
    part += __shfl_xor(part, 32);
    float cur = part + gb[e];

    int idx4[K_]; float val4[K_];
#pragma unroll
    for (int k = 0; k < K_; ++k) {
        float m = cur;
#pragma unroll
        for (int d = 1; d < 64; d <<= 1) m = fmaxf(m, __shfl_xor(m, d));
        unsigned long long b = __ballot(cur == m);
        int l = __ffsll(b) - 1;          // lowest lane -> lowest expert idx (tie-break)
        idx4[k] = l & 31; val4[k] = m;
        if (e == (l & 31)) cur = -INFINITY;
    }
    float mx = val4[0], s = 0.f, wv4[K_];
#pragma unroll
    for (int k = 0; k < K_; ++k) { wv4[k] = expf(val4[k] - mx); s += wv4[k]; }
    float inv = 1.f / s;
    if (lane < K_) {
        int ex = idx4[lane];
        int slot = atomicAdd(&counts[ex], 1);
        token_list[ex * T_ + slot] = t;
        weight_list[ex * T_ + slot] = wv4[lane] * inv;
    }
}

// ---------------- compute phase: A direct from global (L2-resident), B via
// tr_b16 from LDS. A elements assembled in the k-order of the tr-read map:
// frag elem (hi,j) must hold k = 32s + 16hi + 4g + j -> two 8B loads.
#define G_COMPUTE(BUF, KK)                                                     \
    _Pragma("unroll")                                                          \
    for (int s = 0; s < 2; ++s) {                                              \
        short8v afr[4];                                                        \
        _Pragma("unroll")                                                      \
        for (int mi = 0; mi < 4; ++mi) {                                       \
            short4v alo = *(const short4v*)(rp[mi] + (KK) + s * 32 + 4 * g);   \
            short4v ahi = *(const short4v*)(rp[mi] + (KK) + s * 32 + 16 + 4 * g); \
            short8v a;                                                         \
            a[0] = alo[0]; a[1] = alo[1]; a[2] = alo[2]; a[3] = alo[3];        \
            a[4] = ahi[0]; a[5] = ahi[1]; a[6] = ahi[2]; a[7] = ahi[3];        \
            afr[mi] = a;                                                       \
        }                                                                      \
        short4v bl[2], bh[2];                                                  \
        _Pragma("unroll")                                                      \
        for (int ni = 0; ni < 2; ++ni) {                                       \
            unsigned ad = ((BUF) ? trb1 : trb0) + (unsigned)(ni * 2048 + s * 1024); \
            asm volatile("ds_read_b64_tr_b16 %0, %1" : "=v"(bl[ni]) : "v"(ad));     \
            asm volatile("ds_read_b64_tr_b16 %0, %1" : "=v"(bh[ni]) : "v"(ad + 512u)); \
        }                                                                      \
        asm volatile("s_waitcnt lgkmcnt(0)" ::: "memory");                     \
        __builtin_amdgcn_sched_barrier(0);                                     \
        _Pragma("unroll")                                                      \
        for (int ni = 0; ni < 2; ++ni) {                                       \
            short8v b;                                                         \
            b[0] = bl[ni][0]; b[1] = bl[ni][1]; b[2] = bl[ni][2]; b[3] = bl[ni][3]; \
            b[4] = bh[ni][0]; b[5] = bh[ni][1]; b[6] = bh[ni][2]; b[7] = bh[ni][3]; \
            _Pragma("unroll")                                                  \
            for (int mi = 0; mi < 4; ++mi)                                     \
                acc[mi][ni] = __builtin_amdgcn_mfma_f32_16x16x32_bf16(afr[mi], b, acc[mi][ni], 0, 0, 0); \
        }                                                                      \
    }

// ---------------- GEMM1: BM=128 x BN=64 (w1 cols), BK=64; Bs-only dbuf LDS
__global__ __launch_bounds__(256, 5) void gemm1_kernel(
    const unsigned short* __restrict__ hsb, const float* __restrict__ w1,
    const float* __restrict__ b1, const int* __restrict__ counts,
    const int* __restrict__ token_list, unsigned short* __restrict__ actb) {
    int e = blockIdx.z;
    int cnt = counts[e];
    int m0 = blockIdx.y * 128;
    if (m0 >= cnt) return;
    int cb = blockIdx.x * 64;              // w1 col base
    const float* w1e = w1 + (size_t)e * H_ * TWO_I;
    const int* tl = token_list + e * T_;

    __shared__ __align__(16) short Bs[2][64 * 64];   // 16 KB total

    int tid = threadIdx.x;
    int lane = tid & 63;
    int wid = tid >> 6;
    int wm = wid >> 1, wn = wid & 1;
    int g = lane >> 4;
    int l15 = lane & 15;
    unsigned trb0 = (unsigned)(size_t)(&Bs[0][0]) + (unsigned)(lane * 8) + (unsigned)(wn * 4096);
    unsigned trb1 = trb0 + 8192u;

    // A row pointers: 4 gathered bf16 token rows per lane (clamped -> valid mem)
    const unsigned short* rp[4];
#pragma unroll
    for (int mi = 0; mi < 4; ++mi) {
        int gr = m0 + wm * 64 + mi * 16 + l15;
        int gi = (gr < cnt) ? gr : (cnt - 1);
        rp[mi] = hsb + (size_t)tl[gi] * H_;
    }
    // B: 4 float4/thread; k-rows (tid>>4)+16i, cols cb + (tid&15)*4
    int c4 = (tid & 15) << 2;
    const float* bptrB = w1e + (size_t)(tid >> 4) * TWO_I + cb + c4;
    int bwidx[4];
#pragma unroll
    for (int i = 0; i < 4; ++i) {
        int krow = i * 16 + (tid >> 4);
        bwidx[i] = ((c4 >> 4) * 16 + (krow >> 2)) * 64 + (krow & 3) * 16 + (c4 & 15);
    }

    float4v acc[4][2];
#pragma unroll
    for (int i = 0; i < 4; ++i)
#pragma unroll
        for (int j = 0; j < 2; ++j) acc[i][j] = (float4v){0.f, 0.f, 0.f, 0.f};

    float4v rb[4];
    // prologue: tile 0 -> Bs[0]
#pragma unroll
    for (int i = 0; i < 4; ++i) rb[i] = *(const float4v*)(bptrB + (size_t)(i * 16) * TWO_I);
#pragma unroll
    for (int i = 0; i < 4; ++i) *(short4v*)&Bs[0][bwidx[i]] = cvt4(rb[i]);

#pragma unroll 1
    for (int kk = 0; kk < H_; kk += 64) {
        int buf = (kk >> 6) & 1;
        __syncthreads();
        if (kk + 64 < H_) {
#pragma unroll
            for (int i = 0; i < 4; ++i)
                rb[i] = *(const float4v*)(bptrB + (size_t)(kk + 64) * TWO_I + (size_t)(i * 16) * TWO_I);
        }
        G_COMPUTE(buf, kk)
        if (kk + 64 < H_) {
#pragma unroll
            for (int i = 0; i < 4; ++i) *(short4v*)&Bs[buf ^ 1][bwidx[i]] = cvt4(rb[i]);
        }
    }

    // epilogue: deinterleave gate/up (adjacent lanes), swiglu, store bf16 act
    const float* b1e = b1 + (size_t)e * TWO_I;
#pragma unroll
    for (int mi = 0; mi < 4; ++mi) {
#pragma unroll
        for (int r = 0; r < 4; ++r) {
            int gm = m0 + wm * 64 + mi * 16 + g * 4 + r;
#pragma unroll
            for (int ni = 0; ni < 2; ++ni) {
                float v = acc[mi][ni][r];
                float o = __shfl_xor(v, 1);
                if (!(lane & 1) && gm < cnt) {
                    int wc = cb + wn * 32 + ni * 16 + l15;   // even w1 col (gate)
                    float gate = v + b1e[wc];
                    float up   = o + b1e[wc + 1];
                    float sg = 1.f / (1.f + __expf(-1.702f * gate));
                    float av = (up + 1.f) * gate * sg;
                    actb[(size_t)(e * T_ + gm) * I_ + (wc >> 1)] = f2bf(av);
                }
            }
        }
    }
}

// ---------------- GEMM2: BM=128 x BN=64 (h cols), BK=64, K-split x2
__global__ __launch_bounds__(256, 5) void gemm2_kernel(
    const unsigned short* __restrict__ actb, const float* __restrict__ w2,
    const float* __restrict__ b2, const int* __restrict__ counts,
    const int* __restrict__ token_list, const float* __restrict__ weight_list,
    float* __restrict__ out) {
    int e = blockIdx.z;
    int cnt = counts[e];
    int m0 = blockIdx.y * 128;
    if (m0 >= cnt) return;
    int h0 = (blockIdx.x >> 1) * 64;
    int kbase = (blockIdx.x & 1) * 512;
    const float* w2e = w2 + (size_t)e * I_ * H_;
    const int* tl = token_list + e * T_;

    __shared__ __align__(16) short Bs[2][64 * 64];

    int tid = threadIdx.x;
    int lane = tid & 63;
    int wid = tid >> 6;
    int wm = wid >> 1, wn = wid & 1;
    int g = lane >> 4;
    int l15 = lane & 15;
    unsigned trb0 = (unsigned)(size_t)(&Bs[0][0]) + (unsigned)(lane * 8) + (unsigned)(wn * 4096);
    unsigned trb1 = trb0 + 8192u;

    // A row pointers: dense per-expert act rows (clamped)
    const unsigned short* rp[4];
#pragma unroll
    for (int mi = 0; mi < 4; ++mi) {
        int gr = m0 + wm * 64 + mi * 16 + l15;
        int gi = (gr < cnt) ? gr : (cnt - 1);
        rp[mi] = actb + (size_t)(e * T_ + gi) * I_ + kbase;
    }
    // B: 4 float4/thread from w2
    int c4 = (tid & 15) << 2;
    const float* bptrB = w2e + (size_t)(kbase + (tid >> 4)) * H_ + h0 + c4;
    int bwidx[4];
#pragma unroll
    for (int i = 0; i < 4; ++i) {
        int krow = i * 16 + (tid >> 4);
        bwidx[i] = ((c4 >> 4) * 16 + (krow >> 2)) * 64 + (krow & 3) * 16 + (c4 & 15);
    }

    float4v acc[4][2];
#pragma unroll
    for (int i = 0; i < 4; ++i)
#pragma unroll
        for (int j = 0; j < 2; ++j) acc[i][j] = (float4v){0.f, 0.f, 0.f, 0.f};

    float4v rb[4];
    // prologue: tile 0 -> Bs[0]
#pragma unroll
    for (int i = 0; i < 4; ++i) rb[i] = *(const float4v*)(bptrB + (size_t)(i * 16) * H_);
#pragma unroll
    for (int i = 0; i < 4; ++i) *(short4v*)&Bs[0][bwidx[i]] = cvt4(rb[i]);

#pragma unroll 1
    for (int kk = 0; kk < 512; kk += 64) {
        int buf = (kk >> 6) & 1;
        __syncthreads();
        if (kk + 64 < 512) {
#pragma unroll
            for (int i = 0; i < 4; ++i)
                rb[i] = *(const float4v*)(bptrB + (size_t)(kk + 64) * H_ + (size_t)(i * 16) * H_);
        }
        G_COMPUTE(buf, kk)
        if (kk + 64 < 512) {
#pragma unroll
            for (int i = 0; i < 4; ++i) *(short4v*)&Bs[buf ^ 1][bwidx[i]] = cvt4(rb[i]);
        }
    }

    const float* b2e = b2 + (size_t)e * H_;
    const float* wl = weight_list + e * T_;
    bool addbias = (kbase == 0);
#pragma unroll
    for (int mi = 0; mi < 4; ++mi) {
#pragma unroll
        for (int r = 0; r < 4; ++r) {
            int gm = m0 + wm * 64 + mi * 16 + g * 4 + r;
            if (gm < cnt) {
                int t = tl[gm];
                float wgt = wl[gm];
#pragma unroll
                for (int ni = 0; ni < 2; ++ni) {
                    int h = h0 + wn * 32 + ni * 16 + l15;
                    float v = acc[mi][ni][r];
                    if (addbias) v += b2e[h];
                    atomicAdd(&out[(size_t)t * H_ + h], v * wgt);
                }
            }
        }
    }
}

extern "C" void kernel_launch(void* const* d_in, const int* in_sizes, int n_in,
                              void* d_out, int out_size, void* d_ws, size_t ws_size,
                              hipStream_t stream) {
    const float* hs = (const float*)d_in[0];
    const float* gw = (const float*)d_in[1];
    const float* gb = (const float*)d_in[2];
    const float* w1 = (const float*)d_in[3];
    const float* b1 = (const float*)d_in[4];
    const float* w2 = (const float*)d_in[5];
    const float* b2 = (const float*)d_in[6];
    float* out = (float*)d_out;

    char* ws = (char*)d_ws;
    int*   counts      = (int*)ws;                         // 32 ints
    int*   token_list  = (int*)(ws + 4096);                // 32*1024 ints
    float* weight_list = (float*)(ws + 4096 + 131072);     // 32*1024 f32
    unsigned short* hsb  = (unsigned short*)(ws + (1 << 20));        // 2 MB
    unsigned short* actb = (unsigned short*)(ws + (1 << 20) + (2 << 20)); // 64 MB

    prep_kernel<<<(T_ * H_ / 4) / 256, 256, 0, stream>>>(hs, hsb, out, counts);
    router_kernel<<<T_ / 4, 256, 0, stream>>>(hs, gw, gb, counts, token_list, weight_list);
    gemm1_kernel<<<dim3(TWO_I / 64, T_ / 128, E_), 256, 0, stream>>>(
        hsb, w1, b1, counts, token_list, actb);
    gemm2_kernel<<<dim3((H_ / 64) * 2, T_ / 128, E_), 256, 0, stream>>>(
        actb, w2, b2, counts, token_list, weight_list, out);
}

// Round 11
// 227.351 us; speedup vs baseline: 1.7500x; 1.7500x over previous
//
#include <hip/hip_runtime.h>
#include <hip/hip_bf16.h>
#include <math.h>

#define E_ 32
#define K_ 4
#define H_ 1024
#define I_ 1024
#define T_ 1024
#define TWO_I 2048

typedef __attribute__((ext_vector_type(4))) float float4v;
typedef __attribute__((ext_vector_type(8))) short short8v;
typedef __attribute__((ext_vector_type(4))) short short4v;

__device__ __forceinline__ unsigned short f2bf(float f) {
    unsigned u = __float_as_uint(f);
    u = (u + 0x7FFFu + ((u >> 16) & 1u)) >> 16;   // RNE (epilogue scalar use)
    return (unsigned short)u;
}
__device__ __forceinline__ short4v cvt4(float4v v) {
    union { unsigned u[2]; short4v s; } r;
    asm("v_cvt_pk_bf16_f32 %0, %1, %2" : "=v"(r.u[0]) : "v"(v[0]), "v"(v[1]));
    asm("v_cvt_pk_bf16_f32 %0, %1, %2" : "=v"(r.u[1]) : "v"(v[2]), "v"(v[3]));
    return r.s;
}

// ---------------- prep: zero out+counts AND hs f32->bf16 (fused)
__global__ __launch_bounds__(256) void prep_kernel(
    const float* __restrict__ hs, unsigned short* __restrict__ hsb,
    float* __restrict__ out, int* __restrict__ counts) {
    int i = blockIdx.x * 256 + threadIdx.x;
    float4v v = *(const float4v*)(hs + (size_t)i * 4);
    *(short4v*)(hsb + (size_t)i * 4) = cvt4(v);
    *(float4v*)(out + (size_t)i * 4) = (float4v){0.f, 0.f, 0.f, 0.f};
    if (blockIdx.x == 0 && threadIdx.x < E_) counts[threadIdx.x] = 0;
}

// ---------------- router: 4 tokens/block, one wave/token, wave-parallel top-4
__global__ __launch_bounds__(256) void router_kernel(
    const float* __restrict__ hs, const float* __restrict__ gw,
    const float* __restrict__ gb, int* __restrict__ counts,
    int* __restrict__ token_list, float* __restrict__ weight_list) {
    int wv = threadIdx.x >> 6, lane = threadIdx.x & 63;
    int t = blockIdx.x * 4 + wv;
    int e = lane & 31;
    int half = lane >> 5;
    const float* hrow = hs + (size_t)t * H_;
    const float* gcol = gw + e;
    float a0 = 0.f, a1 = 0.f;
    int hb = half * 512;
#pragma unroll 4
    for (int h = 0; h < 512; h += 2) {
        a0 = fmaf(hrow[hb + h],     gcol[(size_t)(hb + h) * E_], a0);
        a1 = fmaf(hrow[hb + h + 1], gcol[(size_t)(hb + h + 1) * E_], a1);
    }
    float part = a0 + a1;
    part += __shfl_xor(part, 32);
    float cur = part + gb[e];

    int idx4[K_]; float val4[K_];
#pragma unroll
    for (int k = 0; k < K_; ++k) {
        float m = cur;
#pragma unroll
        for (int d = 1; d < 64; d <<= 1) m = fmaxf(m, __shfl_xor(m, d));
        unsigned long long b = __ballot(cur == m);
        int l = __ffsll(b) - 1;          // lowest lane -> lowest expert idx
        idx4[k] = l & 31; val4[k] = m;
        if (e == (l & 31)) cur = -INFINITY;
    }
    float mx = val4[0], s = 0.f, wv4[K_];
#pragma unroll
    for (int k = 0; k < K_; ++k) { wv4[k] = expf(val4[k] - mx); s += wv4[k]; }
    float inv = 1.f / s;
    if (lane < K_) {
        int ex = idx4[lane];
        int slot = atomicAdd(&counts[ex], 1);
        token_list[ex * T_ + slot] = t;
        weight_list[ex * T_ + slot] = wv4[lane] * inv;
    }
}

// ---------------- stage: 4 A-issues (bf16, swizzled source) + 4 B-issues (f32)
// A LDS: [128][64] bf16, element (row,k) at byte row*128 + ((k*2)^((row&7)<<4))
// B LDS: [64][64] f32,  element (k,n)  at dword k*64 + (n^(((k>>3)&1)<<4))
#define G_STAGE(BUF, KK, ASRC, BSRC, BSTRIDE)                                  \
    _Pragma("unroll")                                                          \
    for (int i = 0; i < 4; ++i)                                                \
        __builtin_amdgcn_global_load_lds(                                      \
            (const __attribute__((address_space(1))) unsigned int*)(ASRC[i] + (KK)), \
            (__attribute__((address_space(3))) unsigned int*)&As[BUF][(wid * 4 + i) * 512], \
            16, 0, 0);                                                         \
    _Pragma("unroll")                                                          \
    for (int i = 0; i < 4; ++i)                                                \
        __builtin_amdgcn_global_load_lds(                                      \
            (const __attribute__((address_space(1))) unsigned int*)(BSRC[i] + (size_t)(KK) * (BSTRIDE)), \
            (__attribute__((address_space(3))) unsigned int*)&Bsf[BUF][(wid * 4 + i) * 256], \
            16, 0, 0);

// ---------------- compute: A b128 swizzled reads, B b32 swizzled + cvt_pk
#define G_COMPUTE(BUF)                                                         \
    _Pragma("unroll")                                                          \
    for (int s = 0; s < 2; ++s) {                                              \
        short8v afr[4];                                                        \
        _Pragma("unroll")                                                      \
        for (int mi = 0; mi < 4; ++mi) {                                       \
            int row = wm * 64 + mi * 16 + l15;                                 \
            int ab = (s * 64 + g * 16) ^ ((row & 7) << 4);                     \
            afr[mi] = *(const short8v*)((const char*)&As[BUF][0] + row * 128 + ab); \
        }                                                                      \
        _Pragma("unroll")                                                      \
        for (int ni = 0; ni < 2; ++ni) {                                       \
            int n = wn * 32 + ni * 16 + l15;                                   \
            union { unsigned u[4]; short8v s8; } bu;                           \
            _Pragma("unroll")                                                  \
            for (int jj = 0; jj < 4; ++jj) {                                   \
                int k = s * 32 + g * 8 + 2 * jj;                               \
                int q0 = k * 64 + (n ^ (((k >> 3) & 1) << 4));                 \
                float f0 = Bsf[BUF][q0];                                       \
                float f1 = Bsf[BUF][q0 + 64];                                  \
                asm("v_cvt_pk_bf16_f32 %0, %1, %2" : "=v"(bu.u[jj]) : "v"(f0), "v"(f1)); \
            }                                                                  \
            _Pragma("unroll")                                                  \
            for (int mi = 0; mi < 4; ++mi)                                     \
                acc[mi][ni] = __builtin_amdgcn_mfma_f32_16x16x32_bf16(afr[mi], bu.s8, acc[mi][ni], 0, 0, 0); \
        }                                                                      \
    }

// ---------------- GEMM1: BM=128 x BN=64 (w1 cols), BK=64, gload_lds dbuf
__global__ __launch_bounds__(256, 2) void gemm1_kernel(
    const unsigned short* __restrict__ hsb, const float* __restrict__ w1,
    const float* __restrict__ b1, const int* __restrict__ counts,
    const int* __restrict__ token_list, unsigned short* __restrict__ actb) {
    int e = blockIdx.z;
    int cnt = counts[e];
    int m0 = blockIdx.y * 128;
    if (m0 >= cnt) return;
    int cb = blockIdx.x * 64;              // w1 col base
    const float* w1e = w1 + (size_t)e * H_ * TWO_I;
    const int* tl = token_list + e * T_;

    __shared__ __align__(16) short As[2][128 * 64];   // 2 x 16 KB bf16
    __shared__ __align__(16) float Bsf[2][64 * 64];   // 2 x 16 KB f32

    int tid = threadIdx.x;
    int lane = tid & 63;
    int wid = tid >> 6;
    int wm = wid >> 1, wn = wid & 1;
    int g = lane >> 4;
    int l15 = lane & 15;

    // A sources: issue i covers rows (wid*4+i)*8 .. +7; lane covers row +(lane>>3),
    // bytes (lane&7)*16 of the row -> inverse-swizzled source column
    const unsigned short* asrc[4];
#pragma unroll
    for (int i = 0; i < 4; ++i) {
        int r = (wid * 4 + i) * 8 + (lane >> 3);
        int gr = m0 + r;
        int gi = (gr < cnt) ? gr : (cnt - 1);
        int sb = (((lane & 7) * 16) ^ ((r & 7) << 4)) >> 1;   // shorts
        asrc[i] = hsb + (size_t)tl[gi] * H_ + sb;
    }
    // B sources: issue i covers k-rows (wid*4+i)*4 .. +3; lane covers row +(lane>>4),
    // dwords (lane&15)*4 -> inverse-swizzled n
    const float* bsrc[4];
#pragma unroll
    for (int i = 0; i < 4; ++i) {
        int krow = (wid * 4 + i) * 4 + (lane >> 4);
        int ns = ((lane & 15) * 4) ^ (((krow >> 3) & 1) << 4);
        bsrc[i] = w1e + (size_t)krow * TWO_I + cb + ns;
    }

    float4v acc[4][2];
#pragma unroll
    for (int i = 0; i < 4; ++i)
#pragma unroll
        for (int j = 0; j < 2; ++j) acc[i][j] = (float4v){0.f, 0.f, 0.f, 0.f};

    G_STAGE(0, 0, asrc, bsrc, TWO_I)
    __syncthreads();
#pragma unroll 1
    for (int kk = 0; kk < H_; kk += 64) {
        int buf = (kk >> 6) & 1;
        if (kk + 64 < H_) { G_STAGE(buf ^ 1, kk + 64, asrc, bsrc, TWO_I) }
        G_COMPUTE(buf)
        __syncthreads();
    }

    // epilogue: deinterleave gate/up (adjacent lanes), swiglu, store bf16 act
    const float* b1e = b1 + (size_t)e * TWO_I;
#pragma unroll
    for (int mi = 0; mi < 4; ++mi) {
#pragma unroll
        for (int r = 0; r < 4; ++r) {
            int gm = m0 + wm * 64 + mi * 16 + g * 4 + r;
#pragma unroll
            for (int ni = 0; ni < 2; ++ni) {
                float v = acc[mi][ni][r];
                float o = __shfl_xor(v, 1);
                if (!(lane & 1) && gm < cnt) {
                    int wc = cb + wn * 32 + ni * 16 + l15;   // even w1 col (gate)
                    float gate = v + b1e[wc];
                    float up   = o + b1e[wc + 1];
                    float sg = 1.f / (1.f + __expf(-1.702f * gate));
                    float av = (up + 1.f) * gate * sg;
                    actb[(size_t)(e * T_ + gm) * I_ + (wc >> 1)] = f2bf(av);
                }
            }
        }
    }
}

// ---------------- GEMM2: BM=128 x BN=64 (h cols), BK=64, K-split x2
__global__ __launch_bounds__(256, 2) void gemm2_kernel(
    const unsigned short* __restrict__ actb, const float* __restrict__ w2,
    const float* __restrict__ b2, const int* __restrict__ counts,
    const int* __restrict__ token_list, const float* __restrict__ weight_list,
    float* __restrict__ out) {
    int e = blockIdx.z;
    int cnt = counts[e];
    int m0 = blockIdx.y * 128;
    if (m0 >= cnt) return;
    int h0 = (blockIdx.x >> 1) * 64;
    int kbase = (blockIdx.x & 1) * 512;
    const float* w2e = w2 + (size_t)e * I_ * H_;
    const int* tl = token_list + e * T_;

    __shared__ __align__(16) short As[2][128 * 64];
    __shared__ __align__(16) float Bsf[2][64 * 64];

    int tid = threadIdx.x;
    int lane = tid & 63;
    int wid = tid >> 6;
    int wm = wid >> 1, wn = wid & 1;
    int g = lane >> 4;
    int l15 = lane & 15;

    const unsigned short* asrc[4];
#pragma unroll
    for (int i = 0; i < 4; ++i) {
        int r = (wid * 4 + i) * 8 + (lane >> 3);
        int gr = m0 + r;
        int gi = (gr < cnt) ? gr : (cnt - 1);
        int sb = (((lane & 7) * 16) ^ ((r & 7) << 4)) >> 1;
        asrc[i] = actb + (size_t)(e * T_ + gi) * I_ + kbase + sb;
    }
    const float* bsrc[4];
#pragma unroll
    for (int i = 0; i < 4; ++i) {
        int krow = (wid * 4 + i) * 4 + (lane >> 4);
        int ns = ((lane & 15) * 4) ^ (((krow >> 3) & 1) << 4);
        bsrc[i] = w2e + (size_t)(kbase + krow) * H_ + h0 + ns;
    }

    float4v acc[4][2];
#pragma unroll
    for (int i = 0; i < 4; ++i)
#pragma unroll
        for (int j = 0; j < 2; ++j) acc[i][j] = (float4v){0.f, 0.f, 0.f, 0.f};

    G_STAGE(0, 0, asrc, bsrc, H_)
    __syncthreads();
#pragma unroll 1
    for (int kk = 0; kk < 512; kk += 64) {
        int buf = (kk >> 6) & 1;
        if (kk + 64 < 512) { G_STAGE(buf ^ 1, kk + 64, asrc, bsrc, H_) }
        G_COMPUTE(buf)
        __syncthreads();
    }

    const float* b2e = b2 + (size_t)e * H_;
    const float* wl = weight_list + e * T_;
    bool addbias = (kbase == 0);
#pragma unroll
    for (int mi = 0; mi < 4; ++mi) {
#pragma unroll
        for (int r = 0; r < 4; ++r) {
            int gm = m0 + wm * 64 + mi * 16 + g * 4 + r;
            if (gm < cnt) {
                int t = tl[gm];
                float wgt = wl[gm];
#pragma unroll
                for (int ni = 0; ni < 2; ++ni) {
                    int h = h0 + wn * 32 + ni * 16 + l15;
                    float v = acc[mi][ni][r];
                    if (addbias) v += b2e[h];
                    atomicAdd(&out[(size_t)t * H_ + h], v * wgt);
                }
            }
        }
    }
}

extern "C" void kernel_launch(void* const* d_in, const int* in_sizes, int n_in,
                              void* d_out, int out_size, void* d_ws, size_t ws_size,
                              hipStream_t stream) {
    const float* hs = (const float*)d_in[0];
    const float* gw = (const float*)d_in[1];
    const float* gb = (const float*)d_in[2];
    const float* w1 = (const float*)d_in[3];
    const float* b1 = (const float*)d_in[4];
    const float* w2 = (const float*)d_in[5];
    const float* b2 = (const float*)d_in[6];
    float* out = (float*)d_out;

    char* ws = (char*)d_ws;
    int*   counts      = (int*)ws;                         // 32 ints
    int*   token_list  = (int*)(ws + 4096);                // 32*1024 ints
    float* weight_list = (float*)(ws + 4096 + 131072);     // 32*1024 f32
    unsigned short* hsb  = (unsigned short*)(ws + (1 << 20));        // 2 MB
    unsigned short* actb = (unsigned short*)(ws + (1 << 20) + (2 << 20)); // 64 MB

    prep_kernel<<<(T_ * H_ / 4) / 256, 256, 0, stream>>>(hs, hsb, out, counts);
    router_kernel<<<T_ / 4, 256, 0, stream>>>(hs, gw, gb, counts, token_list, weight_list);
    gemm1_kernel<<<dim3(TWO_I / 64, T_ / 128, E_), 256, 0, stream>>>(
        hsb, w1, b1, counts, token_list, actb);
    gemm2_kernel<<<dim3((H_ / 64) * 2, T_ / 128, E_), 256, 0, stream>>>(
        actb, w2, b2, counts, token_list, weight_list, out);
}

// Round 12
// 202.820 us; speedup vs baseline: 1.9617x; 1.1210x over previous
//
#include <hip/hip_runtime.h>
#include <hip/hip_bf16.h>
#include <math.h>

#define E_ 32
#define K_ 4
#define H_ 1024
#define I_ 1024
#define T_ 1024
#define TWO_I 2048

typedef __attribute__((ext_vector_type(4))) float float4v;
typedef __attribute__((ext_vector_type(8))) short short8v;
typedef __attribute__((ext_vector_type(4))) short short4v;

__device__ __forceinline__ unsigned short f2bf(float f) {
    unsigned u = __float_as_uint(f);
    u = (u + 0x7FFFu + ((u >> 16) & 1u)) >> 16;   // RNE (epilogue scalar use only)
    return (unsigned short)u;
}
// packed RNE f32->bf16 via HW instruction: 2 els / instr
__device__ __forceinline__ short4v cvt4(float4v v) {
    union { unsigned u[2]; short4v s; } r;
    asm("v_cvt_pk_bf16_f32 %0, %1, %2" : "=v"(r.u[0]) : "v"(v[0]), "v"(v[1]));
    asm("v_cvt_pk_bf16_f32 %0, %1, %2" : "=v"(r.u[1]) : "v"(v[2]), "v"(v[3]));
    return r.s;
}
// permuted position (shorts) of a 4-aligned k-chunk in a 64-k row, matching
// tr-read k map: k = 32s + 16hi + 4g + j -> p = 32s + 8g + 4hi + j
__device__ __forceinline__ int permpos(int k4) {
    return ((k4 >> 5) << 5) + (((k4 >> 2) & 3) << 3) + (((k4 >> 4) & 1) << 2);
}

// ---------------- prep: zero out+counts AND hs f32->bf16 (fused)
__global__ __launch_bounds__(256) void prep_kernel(
    const float* __restrict__ hs, unsigned short* __restrict__ hsb,
    float* __restrict__ out, int* __restrict__ counts) {
    int i = blockIdx.x * 256 + threadIdx.x;
    float4v v = *(const float4v*)(hs + (size_t)i * 4);
    *(short4v*)(hsb + (size_t)i * 4) = cvt4(v);
    *(float4v*)(out + (size_t)i * 4) = (float4v){0.f, 0.f, 0.f, 0.f};
    if (blockIdx.x == 0 && threadIdx.x < E_) counts[threadIdx.x] = 0;
}

// ---------------- router: 4 tokens/block, one wave/token, wave-parallel top-4
__global__ __launch_bounds__(256) void router_kernel(
    const float* __restrict__ hs, const float* __restrict__ gw,
    const float* __restrict__ gb, int* __restrict__ counts,
    int* __restrict__ token_list, float* __restrict__ weight_list) {
    int wv = threadIdx.x >> 6, lane = threadIdx.x & 63;
    int t = blockIdx.x * 4 + wv;
    int e = lane & 31;
    int half = lane >> 5;
    const float* hrow = hs + (size_t)t * H_;
    const float* gcol = gw + e;
    float a0 = 0.f, a1 = 0.f;
    int hb = half * 512;
#pragma unroll 4
    for (int h = 0; h < 512; h += 2) {
        a0 = fmaf(hrow[hb + h],     gcol[(size_t)(hb + h) * E_], a0);
        a1 = fmaf(hrow[hb + h + 1], gcol[(size_t)(hb + h + 1) * E_], a1);
    }
    float part = a0 + a1;
    part += __shfl_xor(part, 32);
    float cur = part + gb[e];

    int idx4[K_]; float val4[K_];
#pragma unroll
    for (int k = 0; k < K_; ++k) {
        float m = cur;
#pragma unroll
        for (int d = 1; d < 64; d <<= 1) m = fmaxf(m, __shfl_xor(m, d));
        unsigned long long b = __ballot(cur == m);
        int l = __ffsll(b) - 1;          // lowest lane -> lowest expert idx (tie-break)
        idx4[k] = l & 31; val4[k] = m;
        if (e == (l & 31)) cur = -INFINITY;
    }
    float mx = val4[0], s = 0.f, wv4[K_];
#pragma unroll
    for (int k = 0; k < K_; ++k) { wv4[k] = expf(val4[k] - mx); s += wv4[k]; }
    float inv = 1.f / s;
    if (lane < K_) {
        int ex = idx4[lane];
        int slot = atomicAdd(&counts[ex], 1);
        token_list[ex * T_ + slot] = t;
        weight_list[ex * T_ + slot] = wv4[lane] * inv;
    }
}

// ---------------- shared MFMA compute phase (NM m-frags x 2 n-frags, BK=64)
#define G_COMPUTE(BUF, NM, ROWBASE)                                            \
    _Pragma("unroll")                                                          \
    for (int s = 0; s < 2; ++s) {                                              \
        short8v afr[NM];                                                       \
        _Pragma("unroll")                                                      \
        for (int mi = 0; mi < NM; ++mi) {                                      \
            int row = (ROWBASE) + mi * 16 + l15;                               \
            afr[mi] = *(const short8v*)&As[BUF][row * 64 + ((s * 32 + g * 8) ^ sw)]; \
        }                                                                      \
        short4v bl[2], bh[2];                                                  \
        _Pragma("unroll")                                                      \
        for (int ni = 0; ni < 2; ++ni) {                                       \
            unsigned ad = ((BUF) ? trb1 : trb0) + (unsigned)(ni * 2048 + s * 1024); \
            asm volatile("ds_read_b64_tr_b16 %0, %1" : "=v"(bl[ni]) : "v"(ad));     \
            asm volatile("ds_read_b64_tr_b16 %0, %1" : "=v"(bh[ni]) : "v"(ad + 512u)); \
        }                                                                      \
        asm volatile("s_waitcnt lgkmcnt(0)" ::: "memory");                     \
        __builtin_amdgcn_sched_barrier(0);                                     \
        _Pragma("unroll")                                                      \
        for (int ni = 0; ni < 2; ++ni) {                                       \
            short8v b;                                                         \
            b[0] = bl[ni][0]; b[1] = bl[ni][1]; b[2] = bl[ni][2]; b[3] = bl[ni][3]; \
            b[4] = bh[ni][0]; b[5] = bh[ni][1]; b[6] = bh[ni][2]; b[7] = bh[ni][3]; \
            _Pragma("unroll")                                                  \
            for (int mi = 0; mi < NM; ++mi)                                    \
                acc[mi][ni] = __builtin_amdgcn_mfma_f32_16x16x32_bf16(afr[mi], b, acc[mi][ni], 0, 0, 0); \
        }                                                                      \
    }

// ---------------- dbuf K-step: bf16 A (NA x short8), f32 B (4x float4 -> cvt_pk)
// one barrier per step; loads for tile k+1 issued before compute of tile k
#define G_STEP(BUF, KN, BSTRIDE, ISLAST, NA, NM, ROWBASE)                      \
    {                                                                          \
        __syncthreads();                                                       \
        if (!(ISLAST)) {                                                       \
            _Pragma("unroll")                                                  \
            for (int i = 0; i < NA; ++i)                                       \
                ra[i] = aptr[i] ? *(const short8v*)(aptr[i] + (KN)) : z8;      \
            _Pragma("unroll")                                                  \
            for (int i = 0; i < 4; ++i)                                        \
                rb[i] = *(const float4v*)(bptrB + (size_t)(KN) * (BSTRIDE) + (size_t)(i * 16) * (BSTRIDE)); \
        }                                                                      \
        __builtin_amdgcn_sched_barrier(0);                                     \
        G_COMPUTE(BUF, NM, ROWBASE)                                            \
        if (!(ISLAST)) {                                                       \
            _Pragma("unroll")                                                  \
            for (int i = 0; i < NA; ++i) {                                     \
                short8v v = ra[i];                                             \
                short4v lo, hi;                                                \
                lo[0] = v[0]; lo[1] = v[1]; lo[2] = v[2]; lo[3] = v[3];        \
                hi[0] = v[4]; hi[1] = v[5]; hi[2] = v[6]; hi[3] = v[7];        \
                *(short4v*)&As[(BUF) ^ 1][aw0[i]] = lo;                        \
                *(short4v*)&As[(BUF) ^ 1][aw1[i]] = hi;                        \
            }                                                                  \
            _Pragma("unroll")                                                  \
            for (int i = 0; i < 4; ++i) *(short4v*)&Bs[(BUF) ^ 1][bwidx[i]] = cvt4(rb[i]); \
        }                                                                      \
    }

// ---------------- GEMM1: BM=64 x BN=64 (w1 cols), BK=64, 5 blocks/CU
__global__ __launch_bounds__(256, 5) void gemm1_kernel(
    const unsigned short* __restrict__ hsb, const float* __restrict__ w1,
    const float* __restrict__ b1, const int* __restrict__ counts,
    const int* __restrict__ token_list, unsigned short* __restrict__ actb) {
    int e = blockIdx.z;
    int cnt = counts[e];
    int m0 = blockIdx.y * 64;
    if (m0 >= cnt) return;
    int cb = blockIdx.x * 64;              // w1 col base
    const float* w1e = w1 + (size_t)e * H_ * TWO_I;
    const int* tl = token_list + e * T_;

    __shared__ __align__(16) short As[2][64 * 64];   // 16 KB
    __shared__ __align__(16) short Bs[2][64 * 64];   // 16 KB

    int tid = threadIdx.x;
    int lane = tid & 63;
    int wid = tid >> 6;
    int wm = wid >> 1, wn = wid & 1;
    int g = lane >> 4;
    int l15 = lane & 15;
    int sw = (l15 & 7) << 3;
    unsigned trb0 = (unsigned)(size_t)(&Bs[0][0]) + (unsigned)(lane * 8) + (unsigned)(wn * 4096);
    unsigned trb1 = (unsigned)(size_t)(&Bs[1][0]) + (unsigned)(lane * 8) + (unsigned)(wn * 4096);

    // A: 2 short8/thread (gathered bf16 token rows)
    int q = tid & 7;
    const unsigned short* aptr[2]; int aw0[2], aw1[2];
#pragma unroll
    for (int i = 0; i < 2; ++i) {
        int row = i * 32 + (tid >> 3);
        int gr = m0 + row;
        aptr[i] = (gr < cnt) ? hsb + (size_t)tl[gr] * H_ + q * 8 : nullptr;
        int swr = (row & 7) << 3;
        aw0[i] = row * 64 + (permpos(q * 8) ^ swr);
        aw1[i] = row * 64 + (permpos(q * 8 + 4) ^ swr);
    }
    // B: 4 float4/thread; k-rows (tid>>4)+16i, cols cb + (tid&15)*4
    int c4 = (tid & 15) << 2;
    const float* bptrB = w1e + (size_t)(tid >> 4) * TWO_I + cb + c4;
    int bwidx[4];
#pragma unroll
    for (int i = 0; i < 4; ++i) {
        int krow = i * 16 + (tid >> 4);
        bwidx[i] = ((c4 >> 4) * 16 + (krow >> 2)) * 64 + (krow & 3) * 16 + (c4 & 15);
    }

    float4v acc[2][2];
#pragma unroll
    for (int i = 0; i < 2; ++i)
#pragma unroll
        for (int j = 0; j < 2; ++j) acc[i][j] = (float4v){0.f, 0.f, 0.f, 0.f};

    short8v ra[2]; float4v rb[4];
    const short8v z8 = {0, 0, 0, 0, 0, 0, 0, 0};
    // prologue: tile 0 -> buf 0
#pragma unroll
    for (int i = 0; i < 2; ++i) ra[i] = aptr[i] ? *(const short8v*)(aptr[i]) : z8;
#pragma unroll
    for (int i = 0; i < 4; ++i) rb[i] = *(const float4v*)(bptrB + (size_t)(i * 16) * TWO_I);
#pragma unroll
    for (int i = 0; i < 2; ++i) {
        short8v v = ra[i];
        short4v lo, hi;
        lo[0] = v[0]; lo[1] = v[1]; lo[2] = v[2]; lo[3] = v[3];
        hi[0] = v[4]; hi[1] = v[5]; hi[2] = v[6]; hi[3] = v[7];
        *(short4v*)&As[0][aw0[i]] = lo;
        *(short4v*)&As[0][aw1[i]] = hi;
    }
#pragma unroll
    for (int i = 0; i < 4; ++i) *(short4v*)&Bs[0][bwidx[i]] = cvt4(rb[i]);

#pragma unroll 1
    for (int kk = 0; kk < H_; kk += 128) {
        G_STEP(0, kk + 64, TWO_I, false, 2, 2, wm * 32)
        G_STEP(1, kk + 128, TWO_I, (kk + 128) >= H_, 2, 2, wm * 32)
    }

    // epilogue: deinterleave gate/up (adjacent lanes), swiglu, store bf16 act
    const float* b1e = b1 + (size_t)e * TWO_I;
#pragma unroll
    for (int mi = 0; mi < 2; ++mi) {
#pragma unroll
        for (int r = 0; r < 4; ++r) {
            int gm = m0 + wm * 32 + mi * 16 + g * 4 + r;
#pragma unroll
            for (int ni = 0; ni < 2; ++ni) {
                float v = acc[mi][ni][r];
                float o = __shfl_xor(v, 1);
                if (!(lane & 1) && gm < cnt) {
                    int wc = cb + wn * 32 + ni * 16 + l15;   // even w1 col (gate)
                    float gate = v + b1e[wc];
                    float up   = o + b1e[wc + 1];
                    float sg = 1.f / (1.f + __expf(-1.702f * gate));
                    float av = (up + 1.f) * gate * sg;
                    actb[(size_t)(e * T_ + gm) * I_ + (wc >> 1)] = f2bf(av);
                }
            }
        }
    }
}

// ---------------- GEMM2: BM=128 x BN=64 (h cols), BK=64, K-split x2 (R7 form)
__global__ __launch_bounds__(256, 3) void gemm2_kernel(
    const unsigned short* __restrict__ actb, const float* __restrict__ w2,
    const float* __restrict__ b2, const int* __restrict__ counts,
    const int* __restrict__ token_list, const float* __restrict__ weight_list,
    float* __restrict__ out) {
    int e = blockIdx.z;
    int cnt = counts[e];
    int m0 = blockIdx.y * 128;
    if (m0 >= cnt) return;
    int h0 = (blockIdx.x >> 1) * 64;
    int kbase = (blockIdx.x & 1) * 512;
    const float* w2e = w2 + (size_t)e * I_ * H_;
    const int* tl = token_list + e * T_;

    __shared__ __align__(16) short As[2][128 * 64];
    __shared__ __align__(16) short Bs[2][64 * 64];

    int tid = threadIdx.x;
    int lane = tid & 63;
    int wid = tid >> 6;
    int wm = wid >> 1, wn = wid & 1;
    int g = lane >> 4;
    int l15 = lane & 15;
    int sw = (l15 & 7) << 3;
    unsigned trb0 = (unsigned)(size_t)(&Bs[0][0]) + (unsigned)(lane * 8) + (unsigned)(wn * 4096);
    unsigned trb1 = (unsigned)(size_t)(&Bs[1][0]) + (unsigned)(lane * 8) + (unsigned)(wn * 4096);

    // A: 4 short8/thread from actb (dense per-expert rows)
    int q = tid & 7;
    const unsigned short* aptr[4]; int aw0[4], aw1[4];
#pragma unroll
    for (int i = 0; i < 4; ++i) {
        int row = i * 32 + (tid >> 3);
        int gr = m0 + row;
        aptr[i] = (gr < cnt) ? actb + (size_t)(e * T_ + gr) * I_ + kbase + q * 8 : nullptr;
        int swr = (row & 7) << 3;
        aw0[i] = row * 64 + (permpos(q * 8) ^ swr);
        aw1[i] = row * 64 + (permpos(q * 8 + 4) ^ swr);
    }
    // B: 4 float4/thread from w2
    int c4 = (tid & 15) << 2;
    const float* bptrB = w2e + (size_t)(kbase + (tid >> 4)) * H_ + h0 + c4;
    int bwidx[4];
#pragma unroll
    for (int i = 0; i < 4; ++i) {
        int krow = i * 16 + (tid >> 4);
        bwidx[i] = ((c4 >> 4) * 16 + (krow >> 2)) * 64 + (krow & 3) * 16 + (c4 & 15);
    }

    float4v acc[4][2];
#pragma unroll
    for (int i = 0; i < 4; ++i)
#pragma unroll
        for (int j = 0; j < 2; ++j) acc[i][j] = (float4v){0.f, 0.f, 0.f, 0.f};

    short8v ra[4]; float4v rb[4];
    const short8v z8 = {0, 0, 0, 0, 0, 0, 0, 0};
    // prologue: tile 0 -> buf 0
#pragma unroll
    for (int i = 0; i < 4; ++i) ra[i] = aptr[i] ? *(const short8v*)(aptr[i]) : z8;
#pragma unroll
    for (int i = 0; i < 4; ++i) rb[i] = *(const float4v*)(bptrB + (size_t)(i * 16) * H_);
#pragma unroll
    for (int i = 0; i < 4; ++i) {
        short8v v = ra[i];
        short4v lo, hi;
        lo[0] = v[0]; lo[1] = v[1]; lo[2] = v[2]; lo[3] = v[3];
        hi[0] = v[4]; hi[1] = v[5]; hi[2] = v[6]; hi[3] = v[7];
        *(short4v*)&As[0][aw0[i]] = lo;
        *(short4v*)&As[0][aw1[i]] = hi;
    }
#pragma unroll
    for (int i = 0; i < 4; ++i) *(short4v*)&Bs[0][bwidx[i]] = cvt4(rb[i]);

#pragma unroll 1
    for (int kk = 0; kk < 512; kk += 128) {
        G_STEP(0, kk + 64, H_, false, 4, 4, wm * 64)
        G_STEP(1, kk + 128, H_, (kk + 128) >= 512, 4, 4, wm * 64)
    }

    const float* b2e = b2 + (size_t)e * H_;
    const float* wl = weight_list + e * T_;
    bool addbias = (kbase == 0);
#pragma unroll
    for (int mi = 0; mi < 4; ++mi) {
#pragma unroll
        for (int r = 0; r < 4; ++r) {
            int gm = m0 + wm * 64 + mi * 16 + g * 4 + r;
            if (gm < cnt) {
                int t = tl[gm];
                float wgt = wl[gm];
#pragma unroll
                for (int ni = 0; ni < 2; ++ni) {
                    int h = h0 + wn * 32 + ni * 16 + l15;
                    float v = acc[mi][ni][r];
                    if (addbias) v += b2e[h];
                    atomicAdd(&out[(size_t)t * H_ + h], v * wgt);
                }
            }
        }
    }
}

extern "C" void kernel_launch(void* const* d_in, const int* in_sizes, int n_in,
                              void* d_out, int out_size, void* d_ws, size_t ws_size,
                              hipStream_t stream) {
    const float* hs = (const float*)d_in[0];
    const float* gw = (const float*)d_in[1];
    const float* gb = (const float*)d_in[2];
    const float* w1 = (const float*)d_in[3];
    const float* b1 = (const float*)d_in[4];
    const float* w2 = (const float*)d_in[5];
    const float* b2 = (const float*)d_in[6];
    float* out = (float*)d_out;

    char* ws = (char*)d_ws;
    int*   counts      = (int*)ws;                         // 32 ints
    int*   token_list  = (int*)(ws + 4096);                // 32*1024 ints
    float* weight_list = (float*)(ws + 4096 + 131072);     // 32*1024 f32
    unsigned short* hsb  = (unsigned short*)(ws + (1 << 20));        // 2 MB
    unsigned short* actb = (unsigned short*)(ws + (1 << 20) + (2 << 20)); // 64 MB

    prep_kernel<<<(T_ * H_ / 4) / 256, 256, 0, stream>>>(hs, hsb, out, counts);
    router_kernel<<<T_ / 4, 256, 0, stream>>>(hs, gw, gb, counts, token_list, weight_list);
    gemm1_kernel<<<dim3(TWO_I / 64, T_ / 64, E_), 256, 0, stream>>>(
        hsb, w1, b1, counts, token_list, actb);
    gemm2_kernel<<<dim3((H_ / 64) * 2, T_ / 128, E_), 256, 0, stream>>>(
        actb, w2, b2, counts, token_list, weight_list, out);
}